// Round 19
// baseline (829.024 us; speedup 1.0000x reference)
//
#include <hip/hip_runtime.h>
#include <hip/hip_cooperative_groups.h>
#include <stdint.h>

namespace cg = cooperative_groups;

typedef __attribute__((ext_vector_type(8))) short short8;
typedef __attribute__((ext_vector_type(4))) float f32x4;
typedef __attribute__((ext_vector_type(16))) float f32x16;
typedef __attribute__((ext_vector_type(4))) unsigned uint4v;

__device__ __forceinline__ unsigned short f2bf(float f) {
    unsigned u = __float_as_uint(f);
    unsigned r = u + 0x7fffu + ((u >> 16) & 1u);   // RNE
    return (unsigned short)(r >> 16);
}
__device__ __forceinline__ unsigned fenc(float f) {
    unsigned u = __float_as_uint(f);
    return (u & 0x80000000u) ? ~u : (u | 0x80000000u);
}
__device__ __forceinline__ float fdec(unsigned e) {
    unsigned u = (e & 0x80000000u) ? (e & 0x7fffffffu) : ~e;
    return __uint_as_float(u);
}

// ======================= shared device bodies ================================
__device__ __forceinline__ void h_body(
    int blk, int tid, char* smem, int layer,
    const float* __restrict__ xq, const unsigned short* __restrict__ wTb,
    const float* __restrict__ bF, const float* __restrict__ aF,
    unsigned short* __restrict__ hP, float* __restrict__ s1g,
    float* __restrict__ s2g, unsigned* __restrict__ s2mx)
{
    short* xs  = (short*)smem;                 // 64*136 bf16
    short* wsb = (short*)(smem + 17408);       // 128*136 bf16
    float* s2blk = (float*)(smem + 52224);
    int row0 = blk * 64, b = blk >> 5;
    int w = tid >> 6, lane = tid & 63, quad = lane >> 4, l15 = lane & 15;

    for (int c = tid; c < 1024; c += 256) {    // x: 64 rows x 128 k
        int r = c >> 4, kg = c & 15;
        const float* src = &xq[(row0 + r) * 128 + kg * 8];
        f32x4 v0 = *(const f32x4*)src;
        f32x4 v1 = *(const f32x4*)(src + 4);
        short8 o;
        o[0] = (short)f2bf(v0[0]); o[1] = (short)f2bf(v0[1]);
        o[2] = (short)f2bf(v0[2]); o[3] = (short)f2bf(v0[3]);
        o[4] = (short)f2bf(v1[0]); o[5] = (short)f2bf(v1[1]);
        o[6] = (short)f2bf(v1[2]); o[7] = (short)f2bf(v1[3]);
        *(short8*)&xs[r * 136 + kg * 8] = o;
    }
    const unsigned short* wl = wTb + layer * 16384;
    for (int c = tid; c < 2048; c += 256) {    // W^T: 128 n x 128 k
        int n = c >> 4, kg = c & 15;
        *(short8*)&wsb[n * 136 + kg * 8] = *(const short8*)&wl[n * 128 + kg * 8];
    }
    __syncthreads();

    f32x4 acc[8];
#pragma unroll
    for (int t = 0; t < 8; t++) acc[t] = {0.f, 0.f, 0.f, 0.f};
#pragma unroll
    for (int ks = 0; ks < 4; ks++) {
        short8 af = *(const short8*)&xs[(w * 16 + l15) * 136 + ks * 32 + quad * 8];
#pragma unroll
        for (int t = 0; t < 8; t++) {
            short8 bf = *(const short8*)&wsb[(t * 16 + l15) * 136 + ks * 32 + quad * 8];
            acc[t] = __builtin_amdgcn_mfma_f32_16x16x32_bf16(af, bf, acc[t], 0, 0, 0);
        }
    }

    float s1p[4] = {0.f, 0.f, 0.f, 0.f}, s2p[4] = {0.f, 0.f, 0.f, 0.f};
#pragma unroll
    for (int t = 0; t < 8; t++) {
        int colg = t * 16 + l15;
        float bgf = bF[layer * 128 + colg];
        float a1 = aF[layer * 256 + colg];
        float a2 = aF[layer * 256 + 128 + colg];
#pragma unroll
        for (int r = 0; r < 4; r++) {
            float v = acc[t][r] + bgf;
            v = v > 0.f ? v : 0.f;
            acc[t][r] = v;
            s1p[r] = fmaf(v, a1, s1p[r]);
            s2p[r] = fmaf(v, a2, s2p[r]);
        }
    }
#pragma unroll
    for (int r = 0; r < 4; r++) {
#pragma unroll
        for (int off = 1; off < 16; off <<= 1) {
            s1p[r] += __shfl_xor(s1p[r], off, 64);
            s2p[r] += __shfl_xor(s2p[r], off, 64);
        }
    }
    if (l15 == 0) {
#pragma unroll
        for (int r = 0; r < 4; r++) {
            int rowg = row0 + w * 16 + quad * 4 + r;
            s1g[rowg] = s1p[r];
            s2g[rowg] = s2p[r];
        }
    }
    float mx = fmaxf(fmaxf(s2p[0], s2p[1]), fmaxf(s2p[2], s2p[3]));
    mx = fmaxf(mx, __shfl_xor(mx, 16, 64));
    mx = fmaxf(mx, __shfl_xor(mx, 32, 64));
    if (lane == 0) s2blk[w] = mx;
    __syncthreads();               // MFMA reads of wsb done; s2blk visible

    short* st = (short*)wsb;       // transpose buffer (64 rows x stride 130)
#pragma unroll
    for (int t = 0; t < 8; t++)
#pragma unroll
        for (int r = 0; r < 4; r++)
            st[(w * 16 + quad * 4 + r) * 130 + t * 16 + l15] = (short)f2bf(acc[t][r]);
    __syncthreads();
    if (tid == 0) {
        float m2 = fmaxf(fmaxf(s2blk[0], s2blk[1]), fmaxf(s2blk[2], s2blk[3]));
        atomicMax(&s2mx[layer * 8 + b], fenc(m2));
    }
    int i0 = (blk & 31) * 64;
    for (int c = tid; c < 1024; c += 256) {    // hP packed store
        int t = c >> 8, jl2 = (c >> 6) & 3, sl = c & 63;
        int d = t * 32 + (sl & 31);
        int jloc = jl2 * 16 + (sl >> 5) * 8;
        short8 o;
#pragma unroll
        for (int i = 0; i < 8; i++) o[i] = st[(jloc + i) * 130 + d];
        int jtg = (i0 >> 4) + jl2;
        *(short8*)&hP[(((size_t)(b * 4 + t) * 128 + jtg) * 64 + sl) * 8] = o;
    }
}

__device__ __forceinline__ void attn_body(
    int rowblk, int tid, char* smem, int layer,
    const unsigned long long* __restrict__ packed,
    const unsigned short* __restrict__ hP, const float* __restrict__ s1g,
    const float* __restrict__ s2g, const unsigned* __restrict__ s2mx,
    float* __restrict__ xq)
{
    float* red = (float*)smem;                 // 3*32*128 = 48 KB
    float* red_p = (float*)(smem + 49152);     // 4*32 floats
    int b = rowblk >> 6;
    int rowg0 = rowblk * 32;
    int w = tid >> 6, lane = tid & 63;
    int col = lane & 31, khalf = lane >> 5;

    float s1v = s1g[rowg0 + col];              // A row = lane&31
    float s2m = fdec(s2mx[layer * 8 + b]);
    float tmh = s1v + s2m;
    float mhat = fmaxf(tmh, 0.2f * tmh);       // >= all e (leaky monotone)

    f32x16 acc[5];
#pragma unroll
    for (int t = 0; t < 5; t++)
#pragma unroll
        for (int r = 0; r < 16; r++) acc[t][r] = 0.f;

    short8 onesf;                              // ones col 0 B fragment
    {
        short v = (col == 0) ? (short)0x3F80 : (short)0;
        onesf[0]=v;onesf[1]=v;onesf[2]=v;onesf[3]=v;
        onesf[4]=v;onesf[5]=v;onesf[6]=v;onesf[7]=v;
    }

    const float* s2b = s2g + b * 2048;
    const unsigned short* hPb = hP + (size_t)b * 4 * 128 * 64 * 8;
    const unsigned long long* prow = packed + (size_t)(rowg0 + col) * 32;

    for (int jl = 0; jl < 32; jl++) {          // all 128 jt per row-block
        int jt = w + jl * 4;                   // jt>>2==jl, jt&3==w
        unsigned long long word = prow[jl];
        unsigned b8 = (unsigned)(word >> (w * 16 + khalf * 8)) & 0xffu;
        int j0 = jt * 16 + khalf * 8;
        f32x4 sa = *(const f32x4*)&s2b[j0];
        f32x4 sb = *(const f32x4*)&s2b[j0 + 4];
        float sv[8] = {sa[0], sa[1], sa[2], sa[3], sb[0], sb[1], sb[2], sb[3]};
        unsigned rp[8];
#pragma unroll
        for (int jj = 0; jj < 8; jj++) {
            float e = s1v + sv[jj];
            e = fmaxf(e, 0.2f * e);            // leaky_relu
            float pv = __expf(e - mhat);
            rp[jj] = (b8 & (1u << jj)) ? (__float_as_uint(pv) + 0x8000u) : 0u;
        }
        uint4v pk;
        pk[0] = (rp[0] >> 16) | (rp[1] & 0xffff0000u);
        pk[1] = (rp[2] >> 16) | (rp[3] & 0xffff0000u);
        pk[2] = (rp[4] >> 16) | (rp[5] & 0xffff0000u);
        pk[3] = (rp[6] >> 16) | (rp[7] & 0xffff0000u);
        short8 af = *(short8*)&pk;
        short8 bfr[4];
#pragma unroll
        for (int t = 0; t < 4; t++)            // coalesced 64 x 16B
            bfr[t] = *(const short8*)&hPb[(((size_t)t * 128 + jt) * 64 + lane) * 8];
#pragma unroll
        for (int t = 0; t < 4; t++)
            acc[t] = __builtin_amdgcn_mfma_f32_32x32x16_bf16(af, bfr[t], acc[t], 0, 0, 0);
        acc[4] = __builtin_amdgcn_mfma_f32_32x32x16_bf16(af, onesf, acc[4], 0, 0, 0);
    }

    // reduce 4 wave partials; wave 0 normalizes + updates x in place.
    // C/D: col = lane&31, row = (reg&3) + 8*(reg>>2) + 4*(lane>>5)
    __syncthreads();               // prior smem use fully retired
#pragma unroll
    for (int reg = 0; reg < 16; reg++) {
        int row = (reg & 3) + 8 * (reg >> 2) + 4 * khalf;
        if (w > 0) {
#pragma unroll
            for (int t = 0; t < 4; t++)
                red[(w - 1) * 4096 + row * 128 + t * 32 + col] = acc[t][reg];
        }
        if (col == 0) red_p[w * 32 + row] = acc[4][reg];
    }
    __syncthreads();
    if (w == 0) {
#pragma unroll
        for (int reg = 0; reg < 16; reg++) {
            int row = (reg & 3) + 8 * (reg >> 2) + 4 * khalf;
            float p = red_p[row] + red_p[32 + row] + red_p[64 + row] + red_p[96 + row];
            float rl = p > 0.f ? 1.0f / p : 0.f;
#pragma unroll
            for (int t = 0; t < 4; t++) {
                int cidx = row * 128 + t * 32 + col;
                float o = acc[t][reg] + red[cidx] + red[4096 + cidx] + red[8192 + cidx];
                xq[(rowg0 + row) * 128 + t * 32 + col] += o * rl;
            }
        }
    }
    __syncthreads();               // red free for next use
}

// ================= fused cooperative kernel (grid 256 x 256) =================
__global__ __launch_bounds__(256) void k_fused(
    const float* __restrict__ xin, const float* __restrict__ Wf,
    const int* __restrict__ adj, const float* __restrict__ bF,
    const float* __restrict__ aF, float* __restrict__ xq,
    unsigned short* __restrict__ wTb, unsigned* __restrict__ s2mx,
    unsigned long long* __restrict__ packed, unsigned short* __restrict__ hP,
    float* __restrict__ s1g, float* __restrict__ s2g)
{
    cg::grid_group grid = cg::this_grid();
    __shared__ __align__(16) char smem[52304];
    int blk = blockIdx.x, tid = threadIdx.x;
    int w = tid >> 6, lane = tid & 63;

    // phase 0: setup (256 blocks; each packs 2048 words, copies 8192 floats)
    {
        int qbase = blk * 2048 + w * 512;
        for (int k = 0; k < 512; k++) {
            int q = qbase + k;                 // 0..524287
            int row = q >> 5, wd = q & 31;
            int v = adj[row * 2048 + wd * 64 + lane];
            unsigned long long m = __ballot(v > 0);
            if (lane == 0) packed[q] = m;
        }
        int e0 = blk * 8192 + tid * 32;        // x -> fp32 running x
#pragma unroll
        for (int i = 0; i < 8; i++)
            *(f32x4*)(xq + e0 + i * 4) = *(const f32x4*)(xin + e0 + i * 4);
        if (tid < 192) {                       // W -> bf16 W^T
            int c = blk * 192 + tid;
            int l = c >> 14, rem = c & 16383, n = rem >> 7, kk = rem & 127;
            wTb[c] = f2bf(Wf[l * 16384 + kk * 128 + n]);
        }
        if (blk == 0 && tid < 24) s2mx[tid] = fenc(-3e38f);
    }
    grid.sync();

    for (int layer = 0; layer < 3; layer++) {
        h_body(blk, tid, smem, layer, xq, wTb, bF, aF, hP, s1g, s2g, s2mx);
        grid.sync();
        attn_body(blk * 2 + 0, tid, smem, layer, packed, hP, s1g, s2g, s2mx, xq);
        attn_body(blk * 2 + 1, tid, smem, layer, packed, hP, s1g, s2g, s2mx, xq);
        grid.sync();
    }
}

// ===================== fallback path (R17, validated) ========================
__global__ __launch_bounds__(256) void k_setup(
    const float* __restrict__ xin, const float* __restrict__ Wf,
    const int* __restrict__ adj, float* __restrict__ xq,
    unsigned short* __restrict__ wTb, unsigned* __restrict__ s2mx,
    unsigned long long* __restrict__ packed)
{
    int blk = blockIdx.x, tid = threadIdx.x;
    if (blk < 2048) {
        int w = (blk * 256 + tid) >> 6;
        int lane = tid & 63;
        for (int k = 0; k < 64; k++) {
            int q = w * 64 + k;
            int row = q >> 5, wd = q & 31;
            int v = adj[row * 2048 + wd * 64 + lane];
            unsigned long long m = __ballot(v > 0);
            if (lane == 0) packed[q] = m;
        }
    } else if (blk < 4096) {
        int e0 = ((blk - 2048) * 256 + tid) * 4;
        *(f32x4*)(xq + e0) = *(const f32x4*)(xin + e0);
    } else if (blk < 4288) {
        int c = (blk - 4096) * 256 + tid;
        int l = c >> 14, rem = c & 16383, n = rem >> 7, k = rem & 127;
        wTb[c] = f2bf(Wf[l * 16384 + k * 128 + n]);
    } else if (tid < 24) {
        s2mx[tid] = fenc(-3e38f);
    }
}

__global__ __launch_bounds__(256) void k_h(
    const float* __restrict__ xq, const unsigned short* __restrict__ wTb,
    const float* __restrict__ bF, const float* __restrict__ aF, int layer,
    unsigned short* __restrict__ hP, float* __restrict__ s1g,
    float* __restrict__ s2g, unsigned* __restrict__ s2mx)
{
    __shared__ __align__(16) char smem[52304];
    h_body(blockIdx.x, threadIdx.x, smem, layer, xq, wTb, bF, aF, hP, s1g, s2g, s2mx);
}

__global__ __launch_bounds__(256) void k_attn(
    const unsigned long long* __restrict__ packed,
    const unsigned short* __restrict__ hP, const float* __restrict__ s1g,
    const float* __restrict__ s2g, const unsigned* __restrict__ s2mx,
    int layer, float* __restrict__ xq)
{
    __shared__ __align__(16) char smem[52304];
    attn_body(blockIdx.x, threadIdx.x, smem, layer, packed, hP, s1g, s2g, s2mx, xq);
}

extern "C" void kernel_launch(void* const* d_in, const int* in_sizes, int n_in,
                              void* d_out, int out_size, void* d_ws, size_t ws_size,
                              hipStream_t stream) {
    // adj = largest input; among the rest (excluding x = d_in[0]): W > attn_a > bg
    const float* px = (const float*)d_in[0];
    int ia = 1; long amax = -1;
    for (int i = 1; i < n_in; i++)
        if ((long)in_sizes[i] > amax) { amax = in_sizes[i]; ia = i; }
    int rem[8]; int m = 0;
    for (int i = 1; i < n_in && m < 8; i++) if (i != ia) rem[m++] = i;
    for (int i = 0; i < m; i++)
        for (int j = i + 1; j < m; j++)
            if (in_sizes[rem[j]] > in_sizes[rem[i]]) { int t = rem[i]; rem[i] = rem[j]; rem[j] = t; }
    const int*   padj = (const int*)((n_in > 1) ? d_in[ia] : d_in[0]);
    const float* pW = (const float*)((m > 0) ? d_in[rem[0]] : d_in[0]);
    const float* pa = (const float*)((m > 1) ? d_in[rem[1]] : d_in[0]);
    const float* pb = (const float*)((m > 2) ? d_in[rem[2]] : d_in[0]);

    float* xq = (float*)d_out;                        // running fp32 x = output
    char* ws = (char*)d_ws;
    unsigned long long* packed = (unsigned long long*)ws;   // 4 MiB bitmask
    unsigned short* hP = (unsigned short*)(ws + 4194304);   // 4 MiB packed bf16 H
    float* s1 = (float*)(ws + 8388608);                     // 64 KiB
    float* s2 = (float*)(ws + 8454144);                     // 64 KiB
    unsigned* s2mx = (unsigned*)(ws + 8519680);             // 24 slots
    unsigned short* wTb = (unsigned short*)(ws + 8519808);  // 96 KiB bf16 W^T

    void* kargs[] = {
        (void*)&px, (void*)&pW, (void*)&padj, (void*)&pb, (void*)&pa,
        (void*)&xq, (void*)&wTb, (void*)&s2mx, (void*)&packed, (void*)&hP,
        (void*)&s1, (void*)&s2
    };
    hipError_t err = hipLaunchCooperativeKernel((void*)k_fused, dim3(256),
                                                dim3(256), kargs, 0, stream);
    if (err != hipSuccess) {
        // fallback: R17 multi-dispatch path (identical math)
        k_setup<<<4289, 256, 0, stream>>>(px, pW, padj, xq, wTb, s2mx, packed);
        for (int l = 0; l < 3; l++) {
            k_h<<<256, 256, 0, stream>>>(xq, wTb, pb, pa, l, hP, s1, s2, s2mx);
            k_attn<<<512, 256, 0, stream>>>(packed, hP, s1, s2, s2mx, l, xq);
        }
    }
}

// Round 20
// 623.586 us; speedup vs baseline: 1.3294x; 1.3294x over previous
//
#include <hip/hip_runtime.h>
#include <hip/hip_cooperative_groups.h>
#include <stdint.h>

namespace cg = cooperative_groups;

typedef __attribute__((ext_vector_type(8))) short short8;
typedef __attribute__((ext_vector_type(4))) float f32x4;
typedef __attribute__((ext_vector_type(16))) float f32x16;
typedef __attribute__((ext_vector_type(4))) unsigned uint4v;

__device__ __forceinline__ unsigned short f2bf(float f) {
    unsigned u = __float_as_uint(f);
    unsigned r = u + 0x7fffu + ((u >> 16) & 1u);   // RNE
    return (unsigned short)(r >> 16);
}
__device__ __forceinline__ unsigned fenc(float f) {
    unsigned u = __float_as_uint(f);
    return (u & 0x80000000u) ? ~u : (u | 0x80000000u);
}
__device__ __forceinline__ float fdec(unsigned e) {
    unsigned u = (e & 0x80000000u) ? (e & 0x7fffffffu) : ~e;
    return __uint_as_float(u);
}

// ===================== 512-thread bodies (8 waves) ===========================
// h: 64 rows/block; staging by all 8 waves, MFMA/epilogue by waves 0-3.
__device__ __forceinline__ void h_body512(
    int blk, int tid, char* smem, int layer,
    const float* __restrict__ xq, const unsigned short* __restrict__ wTb,
    const float* __restrict__ bF, const float* __restrict__ aF,
    unsigned short* __restrict__ hP, float* __restrict__ s1g,
    float* __restrict__ s2g, unsigned* __restrict__ s2mx)
{
    short* xs  = (short*)smem;                 // 64*136 bf16
    short* wsb = (short*)(smem + 17408);       // 128*136 bf16; reused for transpose
    float* s2blk = (float*)(smem + 52224);
    int row0 = blk * 64, b = blk >> 5;
    int w = tid >> 6, lane = tid & 63, quad = lane >> 4, l15 = lane & 15;

    for (int c = tid; c < 1024; c += 512) {    // x: 64 rows x 128 k
        int r = c >> 4, kg = c & 15;
        const float* src = &xq[(row0 + r) * 128 + kg * 8];
        f32x4 v0 = *(const f32x4*)src;
        f32x4 v1 = *(const f32x4*)(src + 4);
        short8 o;
        o[0] = (short)f2bf(v0[0]); o[1] = (short)f2bf(v0[1]);
        o[2] = (short)f2bf(v0[2]); o[3] = (short)f2bf(v0[3]);
        o[4] = (short)f2bf(v1[0]); o[5] = (short)f2bf(v1[1]);
        o[6] = (short)f2bf(v1[2]); o[7] = (short)f2bf(v1[3]);
        *(short8*)&xs[r * 136 + kg * 8] = o;
    }
    const unsigned short* wl = wTb + layer * 16384;
    for (int c = tid; c < 2048; c += 512) {    // W^T: 128 n x 128 k
        int n = c >> 4, kg = c & 15;
        *(short8*)&wsb[n * 136 + kg * 8] = *(const short8*)&wl[n * 128 + kg * 8];
    }
    __syncthreads();

    f32x4 acc[8];
    if (w < 4) {
#pragma unroll
        for (int t = 0; t < 8; t++) acc[t] = {0.f, 0.f, 0.f, 0.f};
#pragma unroll
        for (int ks = 0; ks < 4; ks++) {
            short8 af = *(const short8*)&xs[(w * 16 + l15) * 136 + ks * 32 + quad * 8];
#pragma unroll
            for (int t = 0; t < 8; t++) {
                short8 bf = *(const short8*)&wsb[(t * 16 + l15) * 136 + ks * 32 + quad * 8];
                acc[t] = __builtin_amdgcn_mfma_f32_16x16x32_bf16(af, bf, acc[t], 0, 0, 0);
            }
        }
        float s1p[4] = {0.f, 0.f, 0.f, 0.f}, s2p[4] = {0.f, 0.f, 0.f, 0.f};
#pragma unroll
        for (int t = 0; t < 8; t++) {
            int colg = t * 16 + l15;
            float bgf = bF[layer * 128 + colg];
            float a1 = aF[layer * 256 + colg];
            float a2 = aF[layer * 256 + 128 + colg];
#pragma unroll
            for (int r = 0; r < 4; r++) {
                float v = acc[t][r] + bgf;
                v = v > 0.f ? v : 0.f;
                acc[t][r] = v;
                s1p[r] = fmaf(v, a1, s1p[r]);
                s2p[r] = fmaf(v, a2, s2p[r]);
            }
        }
#pragma unroll
        for (int r = 0; r < 4; r++) {
#pragma unroll
            for (int off = 1; off < 16; off <<= 1) {
                s1p[r] += __shfl_xor(s1p[r], off, 64);
                s2p[r] += __shfl_xor(s2p[r], off, 64);
            }
        }
        if (l15 == 0) {
#pragma unroll
            for (int r = 0; r < 4; r++) {
                int rowg = row0 + w * 16 + quad * 4 + r;
                s1g[rowg] = s1p[r];
                s2g[rowg] = s2p[r];
            }
        }
        float mx = fmaxf(fmaxf(s2p[0], s2p[1]), fmaxf(s2p[2], s2p[3]));
        mx = fmaxf(mx, __shfl_xor(mx, 16, 64));
        mx = fmaxf(mx, __shfl_xor(mx, 32, 64));
        if (lane == 0) s2blk[w] = mx;
    }
    __syncthreads();               // MFMA reads of wsb done; s2blk visible

    short* st = (short*)wsb;       // transpose buffer (64 rows x stride 130)
    if (w < 4) {
#pragma unroll
        for (int t = 0; t < 8; t++)
#pragma unroll
            for (int r = 0; r < 4; r++)
                st[(w * 16 + quad * 4 + r) * 130 + t * 16 + l15] = (short)f2bf(acc[t][r]);
    }
    __syncthreads();
    if (tid == 0) {
        float m2 = fmaxf(fmaxf(s2blk[0], s2blk[1]), fmaxf(s2blk[2], s2blk[3]));
        atomicMax(&s2mx[layer * 8 + b], fenc(m2));
    }
    int i0 = (blk & 31) * 64;
    for (int c = tid; c < 1024; c += 512) {    // hP packed store
        int t = c >> 8, jl2 = (c >> 6) & 3, sl = c & 63;
        int d = t * 32 + (sl & 31);
        int jloc = jl2 * 16 + (sl >> 5) * 8;
        short8 o;
#pragma unroll
        for (int i = 0; i < 8; i++) o[i] = st[(jloc + i) * 130 + d];
        int jtg = (i0 >> 4) + jl2;
        *(short8*)&hP[(((size_t)(b * 4 + t) * 128 + jtg) * 64 + sl) * 8] = o;
    }
}

// attn: 2 independent 4-wave groups per 512-thr block; group g owns row-block
// blkpair+g (32 rows, all 2048 j). Reductions share one 48 KB buffer, serialized.
__device__ __forceinline__ void attn_body512(
    int blkpair, int tid, char* smem, int layer,
    const unsigned long long* __restrict__ packed,
    const unsigned short* __restrict__ hP, const float* __restrict__ s1g,
    const float* __restrict__ s2g, const unsigned* __restrict__ s2mx,
    float* __restrict__ xq)
{
    float* red = (float*)smem;                 // 3*32*128 = 48 KB (shared)
    float* red_p = (float*)(smem + 49152);     // 2 groups x 128 floats
    int w = tid >> 6, lane = tid & 63;
    int g = w >> 2, wl = w & 3;
    int rowblk = blkpair + g;
    int b = rowblk >> 6;
    int rowg0 = rowblk * 32;
    int col = lane & 31, khalf = lane >> 5;

    float s1v = s1g[rowg0 + col];              // A row = lane&31
    float s2m = fdec(s2mx[layer * 8 + b]);
    float tmh = s1v + s2m;
    float mhat = fmaxf(tmh, 0.2f * tmh);       // >= all e (leaky monotone)

    f32x16 acc[5];
#pragma unroll
    for (int t = 0; t < 5; t++)
#pragma unroll
        for (int r = 0; r < 16; r++) acc[t][r] = 0.f;

    short8 onesf;                              // ones col 0 B fragment
    {
        short v = (col == 0) ? (short)0x3F80 : (short)0;
        onesf[0]=v;onesf[1]=v;onesf[2]=v;onesf[3]=v;
        onesf[4]=v;onesf[5]=v;onesf[6]=v;onesf[7]=v;
    }

    const float* s2b = s2g + b * 2048;
    const unsigned short* hPb = hP + (size_t)b * 4 * 128 * 64 * 8;
    const unsigned long long* prow = packed + (size_t)(rowg0 + col) * 32;

    for (int jl = 0; jl < 32; jl++) {          // all 128 jt per row-block
        int jt = wl + jl * 4;                  // jt>>2==jl, jt&3==wl
        unsigned long long word = prow[jl];
        unsigned b8 = (unsigned)(word >> (wl * 16 + khalf * 8)) & 0xffu;
        int j0 = jt * 16 + khalf * 8;
        f32x4 sa = *(const f32x4*)&s2b[j0];
        f32x4 sb = *(const f32x4*)&s2b[j0 + 4];
        float sv[8] = {sa[0], sa[1], sa[2], sa[3], sb[0], sb[1], sb[2], sb[3]};
        unsigned rp[8];
#pragma unroll
        for (int jj = 0; jj < 8; jj++) {
            float e = s1v + sv[jj];
            e = fmaxf(e, 0.2f * e);            // leaky_relu
            float pv = __expf(e - mhat);
            rp[jj] = (b8 & (1u << jj)) ? (__float_as_uint(pv) + 0x8000u) : 0u;
        }
        uint4v pk;
        pk[0] = (rp[0] >> 16) | (rp[1] & 0xffff0000u);
        pk[1] = (rp[2] >> 16) | (rp[3] & 0xffff0000u);
        pk[2] = (rp[4] >> 16) | (rp[5] & 0xffff0000u);
        pk[3] = (rp[6] >> 16) | (rp[7] & 0xffff0000u);
        short8 af = *(short8*)&pk;
        short8 bfr[4];
#pragma unroll
        for (int t = 0; t < 4; t++)            // coalesced 64 x 16B
            bfr[t] = *(const short8*)&hPb[(((size_t)t * 128 + jt) * 64 + lane) * 8];
#pragma unroll
        for (int t = 0; t < 4; t++)
            acc[t] = __builtin_amdgcn_mfma_f32_32x32x16_bf16(af, bfr[t], acc[t], 0, 0, 0);
        acc[4] = __builtin_amdgcn_mfma_f32_32x32x16_bf16(af, onesf, acc[4], 0, 0, 0);
    }

    // serialized group reductions through the shared red buffer.
    // C/D: col = lane&31, row = (reg&3) + 8*(reg>>2) + 4*(lane>>5)
    __syncthreads();               // prior smem use fully retired
    if (g == 0) {
#pragma unroll
        for (int reg = 0; reg < 16; reg++) {
            int row = (reg & 3) + 8 * (reg >> 2) + 4 * khalf;
            if (wl > 0) {
#pragma unroll
                for (int t = 0; t < 4; t++)
                    red[(wl - 1) * 4096 + row * 128 + t * 32 + col] = acc[t][reg];
            }
            if (col == 0) red_p[wl * 32 + row] = acc[4][reg];
        }
    }
    __syncthreads();
    if (g == 0 && wl == 0) {
#pragma unroll
        for (int reg = 0; reg < 16; reg++) {
            int row = (reg & 3) + 8 * (reg >> 2) + 4 * khalf;
            float p = red_p[row] + red_p[32 + row] + red_p[64 + row] + red_p[96 + row];
            float rl = p > 0.f ? 1.0f / p : 0.f;
#pragma unroll
            for (int t = 0; t < 4; t++) {
                int cidx = row * 128 + t * 32 + col;
                float o = acc[t][reg] + red[cidx] + red[4096 + cidx] + red[8192 + cidx];
                xq[(rowg0 + row) * 128 + t * 32 + col] += o * rl;
            }
        }
    }
    __syncthreads();
    if (g == 1) {
#pragma unroll
        for (int reg = 0; reg < 16; reg++) {
            int row = (reg & 3) + 8 * (reg >> 2) + 4 * khalf;
            if (wl > 0) {
#pragma unroll
                for (int t = 0; t < 4; t++)
                    red[(wl - 1) * 4096 + row * 128 + t * 32 + col] = acc[t][reg];
            }
            if (col == 0) red_p[128 + wl * 32 + row] = acc[4][reg];
        }
    }
    __syncthreads();
    if (g == 1 && wl == 0) {
#pragma unroll
        for (int reg = 0; reg < 16; reg++) {
            int row = (reg & 3) + 8 * (reg >> 2) + 4 * khalf;
            float p = red_p[128 + row] + red_p[160 + row] + red_p[192 + row] + red_p[224 + row];
            float rl = p > 0.f ? 1.0f / p : 0.f;
#pragma unroll
            for (int t = 0; t < 4; t++) {
                int cidx = row * 128 + t * 32 + col;
                float o = acc[t][reg] + red[cidx] + red[4096 + cidx] + red[8192 + cidx];
                xq[(rowg0 + row) * 128 + t * 32 + col] += o * rl;
            }
        }
    }
    __syncthreads();               // red free for next phase
}

// ================= fused cooperative kernel (256 x 512) ======================
__global__ __launch_bounds__(512) void k_fused(
    const float* __restrict__ xin, const float* __restrict__ Wf,
    const int* __restrict__ adj, const float* __restrict__ bF,
    const float* __restrict__ aF, float* __restrict__ xq,
    unsigned short* __restrict__ wTb, unsigned* __restrict__ s2mx,
    unsigned long long* __restrict__ packed, unsigned short* __restrict__ hP,
    float* __restrict__ s1g, float* __restrict__ s2g)
{
    cg::grid_group grid = cg::this_grid();
    __shared__ __align__(16) char smem[52304];
    int blk = blockIdx.x, tid = threadIdx.x;
    int w = tid >> 6, lane = tid & 63;

    // phase 0: setup. 2048 waves x 256 words, 4-way unrolled for MLP.
    {
        int qbase = (blk * 8 + w) * 256;
        for (int k0 = 0; k0 < 256; k0 += 4) {
            int vv[4];
#pragma unroll
            for (int i = 0; i < 4; i++) {
                int q = qbase + k0 + i;
                int row = q >> 5, wd = q & 31;
                vv[i] = adj[row * 2048 + wd * 64 + lane];
            }
#pragma unroll
            for (int i = 0; i < 4; i++) {
                unsigned long long m = __ballot(vv[i] > 0);
                if (lane == 0) packed[qbase + k0 + i] = m;
            }
        }
        int e0 = (blk * 512 + tid) * 16;       // x -> fp32 running x
#pragma unroll
        for (int i = 0; i < 4; i++)
            *(f32x4*)(xq + e0 + i * 4) = *(const f32x4*)(xin + e0 + i * 4);
        if (tid < 192) {                       // W -> bf16 W^T
            int c = blk * 192 + tid;
            int l = c >> 14, rem = c & 16383, n = rem >> 7, kk = rem & 127;
            wTb[c] = f2bf(Wf[l * 16384 + kk * 128 + n]);
        }
        if (blk == 0 && tid < 24) s2mx[tid] = fenc(-3e38f);
    }
    grid.sync();

    for (int layer = 0; layer < 3; layer++) {
        h_body512(blk, tid, smem, layer, xq, wTb, bF, aF, hP, s1g, s2g, s2mx);
        grid.sync();
        attn_body512(blk * 2, tid, smem, layer, packed, hP, s1g, s2g, s2mx, xq);
        grid.sync();
    }
}

// ===================== fallback path (R17-equivalent) ========================
__global__ __launch_bounds__(256) void k_setup(
    const float* __restrict__ xin, const float* __restrict__ Wf,
    const int* __restrict__ adj, float* __restrict__ xq,
    unsigned short* __restrict__ wTb, unsigned* __restrict__ s2mx,
    unsigned long long* __restrict__ packed)
{
    int blk = blockIdx.x, tid = threadIdx.x;
    if (blk < 2048) {
        int w = (blk * 256 + tid) >> 6;
        int lane = tid & 63;
        for (int k = 0; k < 64; k++) {
            int q = w * 64 + k;
            int row = q >> 5, wd = q & 31;
            int v = adj[row * 2048 + wd * 64 + lane];
            unsigned long long m = __ballot(v > 0);
            if (lane == 0) packed[q] = m;
        }
    } else if (blk < 4096) {
        int e0 = ((blk - 2048) * 256 + tid) * 4;
        *(f32x4*)(xq + e0) = *(const f32x4*)(xin + e0);
    } else if (blk < 4288) {
        int c = (blk - 4096) * 256 + tid;
        int l = c >> 14, rem = c & 16383, n = rem >> 7, k = rem & 127;
        wTb[c] = f2bf(Wf[l * 16384 + k * 128 + n]);
    } else if (tid < 24) {
        s2mx[tid] = fenc(-3e38f);
    }
}

__global__ __launch_bounds__(512) void k_h(
    const float* __restrict__ xq, const unsigned short* __restrict__ wTb,
    const float* __restrict__ bF, const float* __restrict__ aF, int layer,
    unsigned short* __restrict__ hP, float* __restrict__ s1g,
    float* __restrict__ s2g, unsigned* __restrict__ s2mx)
{
    __shared__ __align__(16) char smem[52304];
    h_body512(blockIdx.x, threadIdx.x, smem, layer, xq, wTb, bF, aF, hP, s1g, s2g, s2mx);
}

__global__ __launch_bounds__(512) void k_attn(
    const unsigned long long* __restrict__ packed,
    const unsigned short* __restrict__ hP, const float* __restrict__ s1g,
    const float* __restrict__ s2g, const unsigned* __restrict__ s2mx,
    int layer, float* __restrict__ xq)
{
    __shared__ __align__(16) char smem[52304];
    attn_body512(blockIdx.x * 2, threadIdx.x, smem, layer, packed, hP, s1g, s2g, s2mx, xq);
}

extern "C" void kernel_launch(void* const* d_in, const int* in_sizes, int n_in,
                              void* d_out, int out_size, void* d_ws, size_t ws_size,
                              hipStream_t stream) {
    // adj = largest input; among the rest (excluding x = d_in[0]): W > attn_a > bg
    const float* px = (const float*)d_in[0];
    int ia = 1; long amax = -1;
    for (int i = 1; i < n_in; i++)
        if ((long)in_sizes[i] > amax) { amax = in_sizes[i]; ia = i; }
    int rem[8]; int m = 0;
    for (int i = 1; i < n_in && m < 8; i++) if (i != ia) rem[m++] = i;
    for (int i = 0; i < m; i++)
        for (int j = i + 1; j < m; j++)
            if (in_sizes[rem[j]] > in_sizes[rem[i]]) { int t = rem[i]; rem[i] = rem[j]; rem[j] = t; }
    const int*   padj = (const int*)((n_in > 1) ? d_in[ia] : d_in[0]);
    const float* pW = (const float*)((m > 0) ? d_in[rem[0]] : d_in[0]);
    const float* pa = (const float*)((m > 1) ? d_in[rem[1]] : d_in[0]);
    const float* pb = (const float*)((m > 2) ? d_in[rem[2]] : d_in[0]);

    float* xq = (float*)d_out;                        // running fp32 x = output
    char* ws = (char*)d_ws;
    unsigned long long* packed = (unsigned long long*)ws;   // 4 MiB bitmask
    unsigned short* hP = (unsigned short*)(ws + 4194304);   // 4 MiB packed bf16 H
    float* s1 = (float*)(ws + 8388608);                     // 64 KiB
    float* s2 = (float*)(ws + 8454144);                     // 64 KiB
    unsigned* s2mx = (unsigned*)(ws + 8519680);             // 24 slots
    unsigned short* wTb = (unsigned short*)(ws + 8519808);  // 96 KiB bf16 W^T

    void* kargs[] = {
        (void*)&px, (void*)&pW, (void*)&padj, (void*)&pb, (void*)&pa,
        (void*)&xq, (void*)&wTb, (void*)&s2mx, (void*)&packed, (void*)&hP,
        (void*)&s1, (void*)&s2
    };
    hipError_t err = hipLaunchCooperativeKernel((void*)k_fused, dim3(256),
                                                dim3(512), kargs, 0, stream);
    if (err != hipSuccess) {
        // fallback: multi-dispatch path (identical math)
        k_setup<<<4289, 256, 0, stream>>>(px, pW, padj, xq, wTb, s2mx, packed);
        for (int l = 0; l < 3; l++) {
            k_h<<<256, 512, 0, stream>>>(xq, wTb, pb, pa, l, hP, s1, s2, s2mx);
            k_attn<<<256, 512, 0, stream>>>(packed, hP, s1, s2, s2mx, l, xq);
        }
    }
}